// Round 3
// baseline (354.150 us; speedup 1.0000x reference)
//
#include <hip/hip_runtime.h>

// CouplingLayer: 4x conv3x3(SAME) + per-pixel 16x16 expm(A)@x2 + trace logdet.
// Internal compute: f16 MFMA (16x16x32), fp32 accum. Activations NHWC f16.

typedef _Float16 f16;
typedef _Float16 f16x8 __attribute__((ext_vector_type(8)));
typedef _Float16 f16x4 __attribute__((ext_vector_type(4)));
typedef float    f32x4 __attribute__((ext_vector_type(4)));

#define NPX 65536   // B*H*W = 16*64*64

// workspace layout (bytes); ot aliases hB (hB dead after conv2)
constexpr size_t OFF_X1A = 0;                       // 65536*16*2   = 2 MB  (x1 NHWC f16)
constexpr size_t OFF_HA  = 2097152;                 // 65536*128*2  = 16 MB
constexpr size_t OFF_HB  = OFF_HA  + 16777216;      // 16 MB (conv1 out / conv2 in)
constexpr size_t OFF_OT  = OFF_HB;                  // 272*65536*2 = 34 MB (aliases hB)
constexpr size_t OFF_W0P = OFF_OT  + 35651584;      // 5*8*512*2
constexpr size_t OFF_W1P = OFF_W0P + 40960;         // 36*8*512*2
constexpr size_t OFF_W2P = OFF_W1P + 294912;
constexpr size_t OFF_W3P = OFF_W2P + 294912;        // 36*17*512*2 = 626688
// total ~53.2 MB

// ---------------- setup: logdet zero, x1 passthrough copy, x1->NHWC f16, weight packs ----
template<int CI, int CO>
__device__ inline void pack_one(const float* __restrict__ w, f16* __restrict__ pk, int el) {
  constexpr int NT = CO / 16;
  int jj   = el & 7;
  int lane = (el >> 3) & 63;
  int ntkc = el >> 9;
  int nt   = ntkc % NT;
  int kc   = ntkc / NT;
  int k  = kc * 32 + (lane >> 4) * 8 + jj;   // same (g,slot)->k convention as A-side
  int t  = k / CI;
  int ci = k % CI;
  int co = nt * 16 + (lane & 15);
  float v = 0.0f;
  if (t < 9) v = w[(size_t)(co * CI + ci) * 9 + t];
  pk[el] = (f16)v;
}

__global__ __launch_bounds__(256) void setup_k(
    const float* __restrict__ x,
    const float* __restrict__ w0, const float* __restrict__ w1,
    const float* __restrict__ w2, const float* __restrict__ w3,
    float* __restrict__ out, float* __restrict__ logdet,
    f16* __restrict__ x1a, f16* __restrict__ w0p, f16* __restrict__ w1p,
    f16* __restrict__ w2p, f16* __restrict__ w3p)
{
  int tid0 = blockIdx.x * 256 + threadIdx.x;
  int nth  = gridDim.x * 256;
  if (tid0 < 16) logdet[tid0] = 0.0f;
  // x1 passthrough: out[:, :16] = x[:, :16]  (identical flat offsets per batch)
  for (int i = tid0; i < 16 * 16384; i += nth) {
    int n = i >> 14; int off = i & 16383;
    ((f32x4*)out)[(size_t)n * 32768 + off] = ((const f32x4*)x)[(size_t)n * 32768 + off];
  }
  // x1 -> NHWC f16
  for (int p = tid0; p < NPX; p += nth) {
    int n = p >> 12; int rem = p & 4095;
    const float* src = x + (size_t)n * 131072 + rem;
    f16x8 v0, v1;
#pragma unroll
    for (int c = 0; c < 8; ++c) v0[c] = (f16)src[(size_t)c * 4096];
#pragma unroll
    for (int c = 0; c < 8; ++c) v1[c] = (f16)src[(size_t)(c + 8) * 4096];
    *(f16x8*)&x1a[(size_t)p * 16]     = v0;
    *(f16x8*)&x1a[(size_t)p * 16 + 8] = v1;
  }
  for (int i = tid0; i < 5  * 8  * 512; i += nth) pack_one<16, 128>(w0, w0p, i);
  for (int i = tid0; i < 36 * 8  * 512; i += nth) pack_one<128,128>(w1, w1p, i);
  for (int i = tid0; i < 36 * 8  * 512; i += nth) pack_one<128,128>(w2, w2p, i);
  for (int i = tid0; i < 36 * 17 * 512; i += nth) pack_one<128,272>(w3, w3p, i);
}

// ---------------- conv3x3 SAME, implicit GEMM, one block per (n,y) row ----------------
// LDS holds 3 (or 4) input rows x 66 cols x CI (f16), XOR-swizzled for CI=128.
// Each wave owns contiguous co tiles. After K-loop: NHWC store via LDS transpose
// (CO=128 path) or direct channel-major f16 store (conv3 / OT path).
template<int CI, int CO, bool ELU, bool OT>
__global__ __launch_bounds__(256) void conv_k(
    const f16* __restrict__ in, const f16* __restrict__ wpk,
    const float* __restrict__ bias, f16* __restrict__ outp)
{
  constexpr int NT   = CO / 16;
  constexpr int NTW  = (NT + 3) / 4;
  constexpr int NKC  = (9 * CI + 31) / 32;
  constexpr int ROWB = (CI == 16) ? 48 : CI * 2;   // bytes per (row,x) lane of LDS
  constexpr int NROW = (CI == 16) ? 4 : 3;
  constexpr int CPL  = CI / 8;                     // 16B chunks per pixel

  extern __shared__ __align__(16) char smem[];

  const int tid  = threadIdx.x;
  const int wave = tid >> 6;
  const int lane = tid & 63;
  const int g    = lane >> 4;
  const int r15  = lane & 15;
  const int blk  = blockIdx.x;
  const int n    = blk >> 6;
  const int y    = blk & 63;

  // stage rows y-1..y+1 (zeros outside)
  for (int it = tid; it < 3 * 64 * CPL; it += 256) {
    int c8   = it % CPL;
    int xcol = (it / CPL) & 63;
    int r    = it / (64 * CPL);
    int yy   = y + r - 1;
    f16x8 v = {};
    if (yy >= 0 && yy < 64)
      v = *(const f16x8*)&in[((size_t)((n * 64 + yy) * 64 + xcol)) * CI + c8 * 8];
    int xl = xcol + 1;
    int boff = (r * 66 + xl) * ROWB + ((CI == 128) ? ((c8 * 16) ^ ((xl & 7) << 4)) : c8 * 16);
    *(f16x8*)(smem + boff) = v;
  }
  // zero border columns (x = -1 and x = 64)
  for (int it = tid; it < NROW * 2 * CPL; it += 256) {
    int c8   = it % CPL;
    int side = (it / CPL) & 1;
    int r    = it / (2 * CPL);
    int xl   = side ? 65 : 0;
    int boff = (r * 66 + xl) * ROWB + ((CI == 128) ? ((c8 * 16) ^ ((xl & 7) << 4)) : c8 * 16);
    *(f16x8*)(smem + boff) = f16x8{};
  }
  if (CI == 16) { // zero the padding "tap row" (K padded 144->160)
    for (int it = tid; it < 64 * CPL; it += 256) {
      int c8 = it % CPL;
      int xl = (it / CPL) + 1;
      *(f16x8*)(smem + (3 * 66 + xl) * ROWB + c8 * 16) = f16x8{};
    }
  }
  __syncthreads();

  const int nt0  = wave * NTW;
  const int ncnt = (NT - nt0) < NTW ? (NT - nt0) : NTW;

  f32x4 acc[4][NTW];
#pragma unroll
  for (int m = 0; m < 4; ++m)
#pragma unroll
    for (int w = 0; w < NTW; ++w) acc[m][w] = f32x4{0.f, 0.f, 0.f, 0.f};

  f16x8 bcur[NTW], bnxt[NTW];
#pragma unroll
  for (int w = 0; w < NTW; ++w)
    if (w < ncnt) bcur[w] = *(const f16x8*)&wpk[((size_t)((0 * NT + nt0 + w) * 64 + lane)) * 8];

  for (int kc = 0; kc < NKC; ++kc) {
    int k0  = kc * 32 + g * 8;
    int t   = k0 / CI;
    int ci  = k0 % CI;
    int dy  = t / 3;
    int dxm = t - 3 * dy;
    f16x8 a[4];
#pragma unroll
    for (int m = 0; m < 4; ++m) {
      int xl = m * 16 + r15 + dxm;
      int boff = (dy * 66 + xl) * ROWB + ((CI == 128) ? ((ci * 2) ^ ((xl & 7) << 4)) : ci * 2);
      a[m] = *(const f16x8*)(smem + boff);
    }
    if (kc + 1 < NKC) {
#pragma unroll
      for (int w = 0; w < NTW; ++w)
        if (w < ncnt) bnxt[w] = *(const f16x8*)&wpk[((size_t)(((kc + 1) * NT + nt0 + w) * 64 + lane)) * 8];
    }
#pragma unroll
    for (int w = 0; w < NTW; ++w) {
      if (w < ncnt) {
#pragma unroll
        for (int m = 0; m < 4; ++m)
          acc[m][w] = __builtin_amdgcn_mfma_f32_16x16x32_f16(a[m], bcur[w], acc[m][w], 0, 0, 0);
      }
    }
#pragma unroll
    for (int w = 0; w < NTW; ++w) bcur[w] = bnxt[w];
  }

  if (!OT) {
    // CO==128: transpose through LDS (pad 44 dwords -> conflict-light), NHWC f16 store
    __syncthreads();
    float* tile = (float*)smem + (size_t)wave * (64 * 44);
#pragma unroll
    for (int w = 0; w < NTW; ++w)
#pragma unroll
      for (int m = 0; m < 4; ++m)
#pragma unroll
        for (int e = 0; e < 4; ++e)
          tile[(m * 16 + g * 4 + e) * 44 + w * 16 + r15] = acc[m][w][e];
    __syncthreads();
    const int px = lane;
    size_t gbase = ((size_t)((n * 64 + y) * 64 + px)) * CO + nt0 * 16;
#pragma unroll
    for (int c8 = 0; c8 < 4; ++c8) {
      f32x4 v0 = *(const f32x4*)&tile[px * 44 + c8 * 8];
      f32x4 v1 = *(const f32x4*)&tile[px * 44 + c8 * 8 + 4];
      f16x8 h;
#pragma unroll
      for (int j2 = 0; j2 < 4; ++j2) {
        float va = v0[j2] + bias[nt0 * 16 + c8 * 8 + j2];
        float vb = v1[j2] + bias[nt0 * 16 + c8 * 8 + 4 + j2];
        if (ELU) {
          va = va > 0.f ? va : exp2f(va * 1.442695041f) - 1.0f;
          vb = vb > 0.f ? vb : exp2f(vb * 1.442695041f) - 1.0f;
        }
        h[j2]     = (f16)va;
        h[4 + j2] = (f16)vb;
      }
      *(f16x8*)&outp[gbase + c8 * 8] = h;
    }
  } else {
    // conv3: store transposed o_t[co][n][y][x] f16 (coalesced 8B/lane)
#pragma unroll
    for (int w = 0; w < NTW; ++w) {
      if (w < ncnt) {
        int co = (nt0 + w) * 16 + r15;
        float bv = bias[co];
        size_t obase = (size_t)co * 65536 + (size_t)n * 4096 + (size_t)y * 64;
#pragma unroll
        for (int m = 0; m < 4; ++m) {
          f16x4 h;
#pragma unroll
          for (int e = 0; e < 4; ++e) h[e] = (f16)(acc[m][w][e] + bv);
          *(f16x4*)&outp[obase + m * 16 + g * 4] = h;
        }
      }
    }
  }
}

// ---------------- epilogue: tanh-transform, exp(A)@x2 via iterated matvec, trace ------
// 4 lanes per pixel; lane sub owns rows 4sub..4sub+3 of A (A[j][k] = A_mat[4sub+k][j]).
__global__ __launch_bounds__(256) void epi_k(
    const f16* __restrict__ ot, const float* __restrict__ x,
    const float* __restrict__ sc_, const float* __restrict__ sp_,
    const float* __restrict__ rs_, const float* __restrict__ rsh_,
    float* __restrict__ out, float* __restrict__ logdet)
{
  const int tid  = threadIdx.x;
  const int wave = tid >> 6;
  const int lane = tid & 63;
  const int q    = lane >> 2;
  const int sub  = lane & 3;
  const int blk  = blockIdx.x;
  const int n    = blk >> 6;
  const int y    = blk & 63;
  const int xp   = wave * 16 + q;
  const size_t p = (size_t)n * 4096 + y * 64 + xp;

  const float sc = *sc_, sp = *sp_, rs = *rs_, rsh = *rsh_;

  float A[16][4];
  float tr = 0.0f;
#pragma unroll
  for (int j = 0; j < 16; ++j) {
#pragma unroll
    for (int k = 0; k < 4; ++k) {
      int c = 16 + 16 * j + 4 * sub + k;
      float o = (float)ot[(size_t)c * 65536 + p];
      float z = sc * o + sp;
      float e = exp2f(z * 2.885390082f);                    // e^(2z)
      float th = 1.0f - 2.0f * __builtin_amdgcn_rcpf(e + 1.0f);
      float a = rs * th + rsh;
      A[j][k] = a;
      if (sub == (j >> 2) && k == (j & 3)) tr += a;         // diagonal
    }
  }
  float sh[4], xv[4];
#pragma unroll
  for (int k = 0; k < 4; ++k) sh[k] = (float)ot[(size_t)(4 * sub + k) * 65536 + p];
#pragma unroll
  for (int k = 0; k < 4; ++k)
    xv[k] = x[(size_t)n * 131072 + (size_t)(16 + 4 * sub + k) * 4096 + y * 64 + xp];

  float t0 = xv[0], t1 = xv[1], t2 = xv[2], t3 = xv[3];
  float a0 = xv[0], a1 = xv[1], a2 = xv[2], a3 = xv[3];
#pragma unroll
  for (int it = 1; it <= 18; ++it) {
    float ya[16];
#pragma unroll
    for (int s = 0; s < 4; ++s) {
      int src = (lane & 60) | s;
      ya[4 * s + 0] = __shfl(t0, src, 64);
      ya[4 * s + 1] = __shfl(t1, src, 64);
      ya[4 * s + 2] = __shfl(t2, src, 64);
      ya[4 * s + 3] = __shfl(t3, src, 64);
    }
    float n0 = 0.f, n1 = 0.f, n2 = 0.f, n3 = 0.f;
#pragma unroll
    for (int j = 0; j < 16; ++j) {
      n0 += A[j][0] * ya[j];
      n1 += A[j][1] * ya[j];
      n2 += A[j][2] * ya[j];
      n3 += A[j][3] * ya[j];
    }
    const float inv = 1.0f / (float)it;
    t0 = n0 * inv; t1 = n1 * inv; t2 = n2 * inv; t3 = n3 * inv;
    a0 += t0; a1 += t1; a2 += t2; a3 += t3;
  }
  float r0 = a0 + sh[0], r1 = a1 + sh[1], r2 = a2 + sh[2], r3 = a3 + sh[3];
  size_t ob = (size_t)n * 131072 + (size_t)y * 64 + xp;
  out[ob + (size_t)(16 + 4 * sub + 0) * 4096] = r0;
  out[ob + (size_t)(16 + 4 * sub + 1) * 4096] = r1;
  out[ob + (size_t)(16 + 4 * sub + 2) * 4096] = r2;
  out[ob + (size_t)(16 + 4 * sub + 3) * 4096] = r3;

  // trace: quad sum then wave sum of quad totals
  float tt = tr + __shfl_xor(tr, 1, 64);
  tt += __shfl_xor(tt, 2, 64);
  tt += __shfl_xor(tt, 4, 64);
  tt += __shfl_xor(tt, 8, 64);
  tt += __shfl_xor(tt, 16, 64);
  tt += __shfl_xor(tt, 32, 64);
  if (lane == 0) atomicAdd(&logdet[n], tt);
}

extern "C" void kernel_launch(void* const* d_in, const int* in_sizes, int n_in,
                              void* d_out, int out_size, void* d_ws, size_t ws_size,
                              hipStream_t stream) {
  const float* x   = (const float*)d_in[0];
  const float* sc  = (const float*)d_in[1];
  const float* sp  = (const float*)d_in[2];
  const float* rs  = (const float*)d_in[3];
  const float* rsh = (const float*)d_in[4];
  const float* w0  = (const float*)d_in[5];
  const float* b0  = (const float*)d_in[6];
  const float* w1  = (const float*)d_in[7];
  const float* b1  = (const float*)d_in[8];
  const float* w2  = (const float*)d_in[9];
  const float* b2  = (const float*)d_in[10];
  const float* w3  = (const float*)d_in[11];
  const float* b3  = (const float*)d_in[12];

  float* out    = (float*)d_out;
  float* logdet = out + 2097152;
  char* ws = (char*)d_ws;
  f16* x1a = (f16*)(ws + OFF_X1A);
  f16* hA  = (f16*)(ws + OFF_HA);
  f16* hB  = (f16*)(ws + OFF_HB);
  f16* ot  = (f16*)(ws + OFF_OT);   // aliases hB (dead after conv2)
  f16* w0p = (f16*)(ws + OFF_W0P);
  f16* w1p = (f16*)(ws + OFF_W1P);
  f16* w2p = (f16*)(ws + OFF_W2P);
  f16* w3p = (f16*)(ws + OFF_W3P);

  setup_k<<<2048, 256, 0, stream>>>(x, w0, w1, w2, w3, out, logdet, x1a, w0p, w1p, w2p, w3p);
  conv_k<16, 128, true,  false><<<1024, 256, 45056, stream>>>(x1a, w0p, b0, hA);
  conv_k<128, 128, true, false><<<1024, 256, 50688, stream>>>(hA, w1p, b1, hB);
  conv_k<128, 128, true, false><<<1024, 256, 50688, stream>>>(hB, w2p, b2, hA);
  conv_k<128, 272, false, true><<<1024, 256, 50688, stream>>>(hA, w3p, b3, ot);
  epi_k<<<1024, 256, 0, stream>>>(ot, x, sc, sp, rs, rsh, out, logdet);
}

// Round 5
// 271.650 us; speedup vs baseline: 1.3037x; 1.3037x over previous
//
#include <hip/hip_runtime.h>

// CouplingLayer: 4x conv3x3(SAME) + per-pixel 16x16 expm(A)@x2 + trace logdet.
// f16 MFMA (16x16x32), fp32 accum. Activations NHWC f16.
// Conv blocks: 2 output rows, 512 thr (8 waves = 2 row-halves x 4 co-groups),
// grid=512 = exactly 2 blocks/CU (no tail). Weight regs ping-ponged (kc unroll x2).

typedef _Float16 f16;
typedef _Float16 f16x8 __attribute__((ext_vector_type(8)));
typedef float    f32x4 __attribute__((ext_vector_type(4)));

#define NPX 65536   // B*H*W

// workspace layout (bytes); ot aliases hB (hB dead after conv2)
constexpr size_t OFF_X1A = 0;
constexpr size_t OFF_HA  = 2097152;
constexpr size_t OFF_HB  = OFF_HA  + 16777216;
constexpr size_t OFF_OT  = OFF_HB;
constexpr size_t OFF_W0P = OFF_OT  + 35651584;
constexpr size_t OFF_W1P = OFF_W0P + 40960;
constexpr size_t OFF_W2P = OFF_W1P + 294912;
constexpr size_t OFF_W3P = OFF_W2P + 294912;

// ---------------- setup ----------------
template<int CI, int CO>
__device__ inline void pack_one(const float* __restrict__ w, f16* __restrict__ pk, int el) {
  constexpr int NT = CO / 16;
  int jj   = el & 7;
  int lane = (el >> 3) & 63;
  int ntkc = el >> 9;
  int nt   = ntkc % NT;
  int kc   = ntkc / NT;
  int k  = kc * 32 + (lane >> 4) * 8 + jj;
  int t  = k / CI;
  int ci = k % CI;
  int co = nt * 16 + (lane & 15);
  float v = 0.0f;
  if (t < 9) v = w[(size_t)(co * CI + ci) * 9 + t];
  pk[el] = (f16)v;
}

__global__ __launch_bounds__(256) void setup_k(
    const float* __restrict__ x,
    const float* __restrict__ w0, const float* __restrict__ w1,
    const float* __restrict__ w2, const float* __restrict__ w3,
    float* __restrict__ out, float* __restrict__ logdet,
    f16* __restrict__ x1a, f16* __restrict__ w0p, f16* __restrict__ w1p,
    f16* __restrict__ w2p, f16* __restrict__ w3p)
{
  int tid0 = blockIdx.x * 256 + threadIdx.x;
  int nth  = gridDim.x * 256;
  if (tid0 < 16) logdet[tid0] = 0.0f;
  for (int i = tid0; i < 16 * 16384; i += nth) {
    int n = i >> 14; int off = i & 16383;
    ((f32x4*)out)[(size_t)n * 32768 + off] = ((const f32x4*)x)[(size_t)n * 32768 + off];
  }
  for (int p = tid0; p < NPX; p += nth) {
    int n = p >> 12; int rem = p & 4095;
    const float* src = x + (size_t)n * 131072 + rem;
    f16x8 v0, v1;
#pragma unroll
    for (int c = 0; c < 8; ++c) v0[c] = (f16)src[(size_t)c * 4096];
#pragma unroll
    for (int c = 0; c < 8; ++c) v1[c] = (f16)src[(size_t)(c + 8) * 4096];
    *(f16x8*)&x1a[(size_t)p * 16]     = v0;
    *(f16x8*)&x1a[(size_t)p * 16 + 8] = v1;
  }
  for (int i = tid0; i < 5  * 8  * 512; i += nth) pack_one<16, 128>(w0, w0p, i);
  for (int i = tid0; i < 36 * 8  * 512; i += nth) pack_one<128,128>(w1, w1p, i);
  for (int i = tid0; i < 36 * 8  * 512; i += nth) pack_one<128,128>(w2, w2p, i);
  for (int i = tid0; i < 36 * 17 * 512; i += nth) pack_one<128,272>(w3, w3p, i);
}

// ---------------- conv3x3 SAME, implicit GEMM, 2 rows per block ----------------
template<int CI, int CO, bool ELU, bool OT>
__global__ __launch_bounds__(512) void conv_k(
    const f16* __restrict__ in, const f16* __restrict__ wpk,
    const float* __restrict__ bias, f16* __restrict__ outp)
{
  constexpr int NT   = CO / 16;
  constexpr int NTW  = (NT + 3) / 4;
  constexpr int NKC  = (9 * CI + 31) / 32;
  constexpr int ROWB = (CI == 16) ? 48 : CI * 2;
  constexpr int NROW = (CI == 16) ? 5 : 4;   // 4 real rows (+1 zero tap row for CI16)
  constexpr int CPL  = CI / 8;

  extern __shared__ __align__(16) char smem[];

  const int tid  = threadIdx.x;
  const int wave = tid >> 6;
  const int lane = tid & 63;
  const int g    = lane >> 4;
  const int r15  = lane & 15;
  const int mg   = wave >> 2;    // row-half (0: px 0-63 = row y0, 1: px 64-127 = row y0+1)
  const int wq   = wave & 3;     // co-group
  const int blk  = blockIdx.x;
  const int n    = blk >> 5;
  const int y0   = (blk & 31) * 2;

  // stage input rows y0-1 .. y0+2 into LDS rows 0..3
  for (int it = tid; it < 4 * 64 * CPL; it += 512) {
    int c8   = it % CPL;
    int xcol = (it / CPL) & 63;
    int r    = it / (64 * CPL);
    int yy   = y0 + r - 1;
    f16x8 v = {};
    if (yy >= 0 && yy < 64)
      v = *(const f16x8*)&in[((size_t)((n * 64 + yy) * 64 + xcol)) * CI + c8 * 8];
    int xl = xcol + 1;
    int boff = (r * 66 + xl) * ROWB + ((CI == 128) ? ((c8 * 16) ^ ((xl & 7) << 4)) : c8 * 16);
    *(f16x8*)(smem + boff) = v;
  }
  // zero border columns x=-1, x=64 for all rows (incl. tap row for CI16)
  for (int it = tid; it < NROW * 2 * CPL; it += 512) {
    int c8   = it % CPL;
    int side = (it / CPL) & 1;
    int r    = it / (2 * CPL);
    int xl   = side ? 65 : 0;
    int boff = (r * 66 + xl) * ROWB + ((CI == 128) ? ((c8 * 16) ^ ((xl & 7) << 4)) : c8 * 16);
    *(f16x8*)(smem + boff) = f16x8{};
  }
  if (CI == 16) { // zero tap row (row 4) cols 1..64 — K padded 144->160 reads dy==3
    for (int it = tid; it < 64 * CPL; it += 512) {
      int c8 = it % CPL;
      int xl = it / CPL + 1;
      *(f16x8*)(smem + (4 * 66 + xl) * ROWB + c8 * 16) = f16x8{};
    }
  }
  __syncthreads();

  // balanced co-tile split
  constexpr int TB = NT >> 2;
  constexpr int TR = NT & 3;
  const int ncnt = TB + (wq < TR ? 1 : 0);
  const int nt0  = wq * TB + (wq < TR ? wq : TR);

  f32x4 acc[4][NTW];
#pragma unroll
  for (int m = 0; m < 4; ++m)
#pragma unroll
    for (int w = 0; w < NTW; ++w) acc[m][w] = f32x4{0.f, 0.f, 0.f, 0.f};

  f16x8 b0[NTW], b1[NTW];

  auto loadB = [&](f16x8* bb, int kc) {
#pragma unroll
    for (int w = 0; w < NTW; ++w)
      if (w < ncnt) bb[w] = *(const f16x8*)&wpk[((size_t)((kc * NT + nt0 + w) * 64 + lane)) * 8];
  };
  auto step = [&](const f16x8* bb, int kc) {
    int k0  = kc * 32 + g * 8;
    int t   = k0 / CI;
    int ci  = k0 % CI;
    int dy  = t / 3;
    int dxm = t - 3 * dy;
    int ridx = mg + dy;
    if (CI == 16) ridx = (dy == 3) ? 4 : ridx;   // padded taps -> zero row
    f16x8 a[4];
#pragma unroll
    for (int m = 0; m < 4; ++m) {
      int xl = m * 16 + r15 + dxm;
      int boff = (ridx * 66 + xl) * ROWB + ((CI == 128) ? ((ci * 2) ^ ((xl & 7) << 4)) : ci * 2);
      a[m] = *(const f16x8*)(smem + boff);
    }
#pragma unroll
    for (int w = 0; w < NTW; ++w) {
      if (w < ncnt) {
#pragma unroll
        for (int m = 0; m < 4; ++m)
          acc[m][w] = __builtin_amdgcn_mfma_f32_16x16x32_f16(a[m], bb[w], acc[m][w], 0, 0, 0);
      }
    }
  };

  loadB(b0, 0);
  for (int kc = 0; kc + 2 <= NKC; kc += 2) {
    loadB(b1, kc + 1);
    step(b0, kc);
    if (kc + 2 < NKC) loadB(b0, kc + 2);
    step(b1, kc + 1);
  }
  if (NKC & 1) step(b0, NKC - 1);

  if (!OT) {
    // stage f16 NHWC tile [128 px][128 co] in LDS (XOR-swizzled), then linear copy-out
    __syncthreads();
#pragma unroll
    for (int w = 0; w < NTW; ++w) {
      if (w < ncnt) {
#pragma unroll
        for (int m = 0; m < 4; ++m)
#pragma unroll
          for (int e = 0; e < 4; ++e) {
            int px = mg * 64 + m * 16 + g * 4 + e;
            int co = (nt0 + w) * 16 + r15;
            float v = acc[m][w][e] + bias[co];
            if (ELU) v = v > 0.f ? v : exp2f(v * 1.442695041f) - 1.0f;
            *(f16*)(smem + px * 256 + ((co * 2) ^ ((px & 7) << 5))) = (f16)v;
          }
      }
    }
    __syncthreads();
    // block's output region is globally contiguous: 128 px * 128 co * 2B = 32 KB
    for (int i = tid; i < 2048; i += 512) {
      int px = i >> 4, c = i & 15;
      f16x8 v = *(const f16x8*)(smem + px * 256 + ((c * 16) ^ ((px & 7) << 5)));
      *(f16x8*)&outp[(size_t)blk * 16384 + (size_t)i * 8] = v;
    }
  } else {
    // conv3: stage [co 272][px 128] f16 in LDS, then copy to o_t[co][n][y][x]
    __syncthreads();
#pragma unroll
    for (int w = 0; w < NTW; ++w) {
      if (w < ncnt) {
#pragma unroll
        for (int m = 0; m < 4; ++m)
#pragma unroll
          for (int e = 0; e < 4; ++e) {
            int px = mg * 64 + m * 16 + g * 4 + e;
            int co = (nt0 + w) * 16 + r15;
            float v = acc[m][w][e] + bias[co];
            *(f16*)(smem + co * 256 + ((px * 2) ^ ((co & 7) << 4))) = (f16)v;
          }
      }
    }
    __syncthreads();
    for (int i = tid; i < NT * 256; i += 512) {   // 272 co * 16 chunks
      int co = i >> 4, c = i & 15;
      f16x8 v = *(const f16x8*)(smem + co * 256 + ((c * 16) ^ ((co & 7) << 4)));
      *(f16x8*)&outp[(size_t)co * 65536 + (size_t)n * 4096 + (size_t)y0 * 64 + c * 8] = v;
    }
  }
}

// ---------------- epilogue: tanh, exp(A)@x2 via iterated matvec, trace ------
__global__ __launch_bounds__(256) void epi_k(
    const f16* __restrict__ ot, const float* __restrict__ x,
    const float* __restrict__ sc_, const float* __restrict__ sp_,
    const float* __restrict__ rs_, const float* __restrict__ rsh_,
    float* __restrict__ out, float* __restrict__ logdet)
{
  const int tid  = threadIdx.x;
  const int wave = tid >> 6;
  const int lane = tid & 63;
  const int q    = lane >> 2;
  const int sub  = lane & 3;
  const int blk  = blockIdx.x;
  const int n    = blk >> 6;
  const int y    = blk & 63;
  const int xp   = wave * 16 + q;
  const size_t p = (size_t)n * 4096 + y * 64 + xp;

  const float sc = *sc_, sp = *sp_, rs = *rs_, rsh = *rsh_;

  float A[16][4];
  float tr = 0.0f;
#pragma unroll
  for (int j = 0; j < 16; ++j) {
#pragma unroll
    for (int k = 0; k < 4; ++k) {
      int c = 16 + 16 * j + 4 * sub + k;
      float o = (float)ot[(size_t)c * 65536 + p];
      float z = sc * o + sp;
      float e = exp2f(z * 2.885390082f);
      float th = 1.0f - 2.0f * __builtin_amdgcn_rcpf(e + 1.0f);
      float a = rs * th + rsh;
      A[j][k] = a;
      if (sub == (j >> 2) && k == (j & 3)) tr += a;
    }
  }
  float sh[4], xv[4];
#pragma unroll
  for (int k = 0; k < 4; ++k) sh[k] = (float)ot[(size_t)(4 * sub + k) * 65536 + p];
#pragma unroll
  for (int k = 0; k < 4; ++k)
    xv[k] = x[(size_t)n * 131072 + (size_t)(16 + 4 * sub + k) * 4096 + y * 64 + xp];

  float t0 = xv[0], t1 = xv[1], t2 = xv[2], t3 = xv[3];
  float a0 = xv[0], a1 = xv[1], a2 = xv[2], a3 = xv[3];
#pragma unroll
  for (int it = 1; it <= 18; ++it) {
    float ya[16];
#pragma unroll
    for (int s = 0; s < 4; ++s) {
      int src = (lane & 60) | s;
      ya[4 * s + 0] = __shfl(t0, src, 64);
      ya[4 * s + 1] = __shfl(t1, src, 64);
      ya[4 * s + 2] = __shfl(t2, src, 64);
      ya[4 * s + 3] = __shfl(t3, src, 64);
    }
    float n0 = 0.f, n1 = 0.f, n2 = 0.f, n3 = 0.f;
#pragma unroll
    for (int j = 0; j < 16; ++j) {
      n0 += A[j][0] * ya[j];
      n1 += A[j][1] * ya[j];
      n2 += A[j][2] * ya[j];
      n3 += A[j][3] * ya[j];
    }
    const float inv = 1.0f / (float)it;
    t0 = n0 * inv; t1 = n1 * inv; t2 = n2 * inv; t3 = n3 * inv;
    a0 += t0; a1 += t1; a2 += t2; a3 += t3;
  }
  float r0 = a0 + sh[0], r1 = a1 + sh[1], r2 = a2 + sh[2], r3 = a3 + sh[3];
  size_t ob = (size_t)n * 131072 + (size_t)y * 64 + xp;
  out[ob + (size_t)(16 + 4 * sub + 0) * 4096] = r0;
  out[ob + (size_t)(16 + 4 * sub + 1) * 4096] = r1;
  out[ob + (size_t)(16 + 4 * sub + 2) * 4096] = r2;
  out[ob + (size_t)(16 + 4 * sub + 3) * 4096] = r3;

  float tt = tr + __shfl_xor(tr, 1, 64);
  tt += __shfl_xor(tt, 2, 64);
  tt += __shfl_xor(tt, 4, 64);
  tt += __shfl_xor(tt, 8, 64);
  tt += __shfl_xor(tt, 16, 64);
  tt += __shfl_xor(tt, 32, 64);
  if (lane == 0) atomicAdd(&logdet[n], tt);
}

extern "C" void kernel_launch(void* const* d_in, const int* in_sizes, int n_in,
                              void* d_out, int out_size, void* d_ws, size_t ws_size,
                              hipStream_t stream) {
  const float* x   = (const float*)d_in[0];
  const float* sc  = (const float*)d_in[1];
  const float* sp  = (const float*)d_in[2];
  const float* rs  = (const float*)d_in[3];
  const float* rsh = (const float*)d_in[4];
  const float* w0  = (const float*)d_in[5];
  const float* b0  = (const float*)d_in[6];
  const float* w1  = (const float*)d_in[7];
  const float* b1  = (const float*)d_in[8];
  const float* w2  = (const float*)d_in[9];
  const float* b2  = (const float*)d_in[10];
  const float* w3  = (const float*)d_in[11];
  const float* b3  = (const float*)d_in[12];

  float* out    = (float*)d_out;
  float* logdet = out + 2097152;
  char* ws = (char*)d_ws;
  f16* x1a = (f16*)(ws + OFF_X1A);
  f16* hA  = (f16*)(ws + OFF_HA);
  f16* hB  = (f16*)(ws + OFF_HB);
  f16* ot  = (f16*)(ws + OFF_OT);   // aliases hB (dead after conv2)
  f16* w0p = (f16*)(ws + OFF_W0P);
  f16* w1p = (f16*)(ws + OFF_W1P);
  f16* w2p = (f16*)(ws + OFF_W2P);
  f16* w3p = (f16*)(ws + OFF_W3P);

  setup_k<<<2048, 256, 0, stream>>>(x, w0, w1, w2, w3, out, logdet, x1a, w0p, w1p, w2p, w3p);
  conv_k<16, 128, true,  false><<<512, 512, 32768, stream>>>(x1a, w0p, b0, hA);
  conv_k<128, 128, true, false><<<512, 512, 67584, stream>>>(hA, w1p, b1, hB);
  conv_k<128, 128, true, false><<<512, 512, 67584, stream>>>(hB, w2p, b2, hA);
  conv_k<128, 272, false, true><<<512, 512, 69632, stream>>>(hA, w3p, b3, ot);
  epi_k<<<1024, 256, 0, stream>>>(ot, x, sc, sp, rs, rsh, out, logdet);
}